// Round 1
// baseline (669.965 us; speedup 1.0000x reference)
//
#include <hip/hip_runtime.h>
#include <hip/hip_bf16.h>
#include <stdint.h>

#define HIDDEN  1024
#define FFN     3584
#define NE      8
#define NTOK    2048
#define CAP     2048
#define OUT_ELEMS (NTOK * HIDDEN)   /* 2097152 */

/* ---- workspace layout (bytes) ---- */
#define X_OFF   0u                          /* x as bf16: 2048*1024*2 = 4 MiB   */
#define CNT_OFF (4u*1024u*1024u)            /* 8 int counters                   */
#define TOK_OFF (CNT_OFF + 256u)            /* token lists: 8*2048*4 = 64 KiB   */
#define WGT_OFF (TOK_OFF + 65536u)          /* combine weights: 64 KiB          */
#define ACT_OFF (WGT_OFF + 65536u)          /* packed act bf16: 4096*3584*2     */
#define ACT_SZ  (4096u * 3584u * 2u)        /* 29360128                         */
#define WGU_OFF (ACT_OFF + ACT_SZ)          /* bf16 tiled gate/up weights       */
#define WGU_SZ  (8u*56u*16u*16384u)         /* 117440512 (112 MiB)              */
#define WDB_OFF (WGU_OFF + WGU_SZ)          /* bf16 tiled down weights          */
#define WDB_SZ  (8u*8u*56u*16384u)          /* 58720256 (56 MiB)                */
#define WS_NEED ((size_t)WDB_OFF + (size_t)WDB_SZ)

typedef __attribute__((ext_vector_type(8))) short short8;
typedef __attribute__((ext_vector_type(4))) float floatx4;

static __device__ __forceinline__ uint32_t f2bf(float f) {
  union { float f; uint32_t u; } v; v.f = f;
  return (v.u + 0x7FFFu + ((v.u >> 16) & 1u)) >> 16;   /* RNE */
}
static __device__ __forceinline__ uint32_t pack2(float lo, float hi) {
  return f2bf(lo) | (f2bf(hi) << 16);
}
union S8U { uint4 u; short8 s; };
static __device__ __forceinline__ short8 as_short8(uint4 v) { S8U x; x.u = v; return x.s; }

/* async global -> LDS, 16B per lane; LDS dest is wave-uniform base + lane*16 */
static __device__ __forceinline__ void ld_g2l16(const void* g, void* l) {
  __builtin_amdgcn_global_load_lds(
      (const __attribute__((address_space(1))) void*)g,
      (__attribute__((address_space(3))) void*)l, 16, 0, 0);
}

/* ---- zero output accumulation region + expert counters ---- */
__global__ __launch_bounds__(256) void moe_prep(float4* __restrict__ out4,
                                                int* __restrict__ cnt) {
  uint32_t i = blockIdx.x * 256u + threadIdx.x;
  out4[i] = make_float4(0.f, 0.f, 0.f, 0.f);
  if (blockIdx.x == 0 && threadIdx.x < NE) cnt[threadIdx.x] = 0;
}

/* ---- x fp32 -> bf16 ---- */
__global__ __launch_bounds__(256) void moe_convert(const float4* __restrict__ x4,
                                                   uint4* __restrict__ xb) {
  uint32_t g = blockIdx.x * 256u + threadIdx.x;
  float4 a = x4[2u*g], b = x4[2u*g + 1u];
  xb[g] = make_uint4(pack2(a.x, a.y), pack2(a.z, a.w),
                     pack2(b.x, b.y), pack2(b.z, b.w));
}

/* ---- router: one wave per token ---- */
__global__ __launch_bounds__(256) void moe_router(
    const float* __restrict__ x, const float* __restrict__ gw,
    float* __restrict__ logits, int* __restrict__ cnt,
    int* __restrict__ tok, float* __restrict__ wgt)
{
  const int t = blockIdx.x * 4 + (threadIdx.x >> 6);
  const int lane = threadIdx.x & 63;
  const float* xr = x + (size_t)t * HIDDEN;
  float a[NE];
#pragma unroll
  for (int e = 0; e < NE; ++e) a[e] = 0.f;
  for (int hh = 0; hh < HIDDEN / 64; ++hh) {
    float xv = xr[hh * 64 + lane];
#pragma unroll
    for (int e = 0; e < NE; ++e) a[e] += xv * gw[e * HIDDEN + hh * 64 + lane];
  }
#pragma unroll
  for (int off = 32; off > 0; off >>= 1) {
#pragma unroll
    for (int e = 0; e < NE; ++e) a[e] += __shfl_xor(a[e], off);
  }
  if (lane == 0) {
#pragma unroll
    for (int e = 0; e < NE; ++e) logits[t * NE + e] = a[e];
    int i0 = 0; float v0 = a[0];
#pragma unroll
    for (int e = 1; e < NE; ++e) if (a[e] > v0) { v0 = a[e]; i0 = e; }
    int i1 = (i0 == 0) ? 1 : 0; float v1 = a[i1];
#pragma unroll
    for (int e = 0; e < NE; ++e) if (e != i0 && a[e] > v1) { v1 = a[e]; i1 = e; }
    float w0 = 1.f / (1.f + __expf(v1 - v0));
    float w1 = 1.f - w0;
    int p0 = atomicAdd(&cnt[i0], 1); tok[i0 * CAP + p0] = t; wgt[i0 * CAP + p0] = w0;
    int p1 = atomicAdd(&cnt[i1], 1); tok[i1 * CAP + p1] = t; wgt[i1 * CAP + p1] = w1;
  }
}

/* ==== weight preconvert: fp32 -> bf16, GEMM-native swizzled tile layout ====
 * Image per (e, fb, kt): 1024 uint4 (16 KiB). Word (kp,n) = {bf16 W[k0+2kp][col],
 * bf16 W[k0+2kp+1][col]} stored at widx = kp*128 + (n ^ (((kp>>2)&1)<<4)).
 * This is bit-identical to what the old in-GEMM staging produced in LDS.      */
__global__ __launch_bounds__(256) void moe_wconv_gu(const float* __restrict__ wgu,
                                                    uint4* __restrict__ wgub) {
  const int kt = blockIdx.x, fb = blockIdx.y, e = blockIdx.z;
  const int f0 = fb * 64, k0 = kt * 64;
  const float* wB = wgu + (size_t)e * HIDDEN * (2 * FFN);
  uint4* dst = wgub + ((size_t)(e * 56 + fb) * 16 + kt) * 1024;
#pragma unroll
  for (int it = 0; it < 4; ++it) {
    int mid = it * 256 + threadIdx.x;
    int kp = mid >> 5;
    int n  = (mid & 31) * 4;
    int col = f0 + ((n >> 6) << 5) + (n & 31) + (((n >> 5) & 1) ? FFN : 0);
    const float* src = wB + (size_t)(k0 + 2 * kp) * (2 * FFN) + col;
    float4 r0 = *(const float4*)src;
    float4 r1 = *(const float4*)(src + 2 * FFN);
    dst[kp * 32 + ((n >> 2) ^ (((kp >> 2) & 1) << 2))] =
        make_uint4(pack2(r0.x, r1.x), pack2(r0.y, r1.y),
                   pack2(r0.z, r1.z), pack2(r0.w, r1.w));
  }
}

__global__ __launch_bounds__(256) void moe_wconv_d(const float* __restrict__ wd,
                                                   uint4* __restrict__ wdb) {
  const int kt = blockIdx.x, nb = blockIdx.y, e = blockIdx.z;
  const int n0 = nb * 128, k0 = kt * 64;
  const float* wB = wd + (size_t)e * FFN * HIDDEN;
  uint4* dst = wdb + ((size_t)(e * 8 + nb) * 56 + kt) * 1024;
#pragma unroll
  for (int it = 0; it < 4; ++it) {
    int mid = it * 256 + threadIdx.x;
    int kp = mid >> 5;
    int n  = (mid & 31) * 4;
    const float* src = wB + (size_t)(k0 + 2 * kp) * HIDDEN + n0 + n;
    float4 r0 = *(const float4*)src;
    float4 r1 = *(const float4*)(src + HIDDEN);
    dst[kp * 32 + ((n >> 2) ^ (((kp >> 2) & 1) << 2))] =
        make_uint4(pack2(r0.x, r1.x), pack2(r0.y, r1.y),
                   pack2(r0.z, r1.z), pack2(r0.w, r1.w));
  }
}

/* ==== grouped GEMM 1 (fast): bf16 tiled B via global_load_lds ==== */
__global__ __launch_bounds__(256) void moe_gateup(
    const uint4* __restrict__ xb, const uint4* __restrict__ wgub,
    const int* __restrict__ cnt, const int* __restrict__ tok,
    unsigned short* __restrict__ act)
{
  const int e  = blockIdx.z;
  const int m0 = blockIdx.y * 128;
  const int fb = blockIdx.x;
  const int f0 = fb * 64;
  const int cn = cnt[e];
  if (m0 >= cn) return;
  int basev = 0;
#pragma unroll
  for (int i = 0; i < NE; ++i) { int ci = cnt[i]; if (i < e) basev += ci; }

  __shared__ uint4 As[1024];     /* image identical to old kernel */
  __shared__ uint4 Bs4[1024];
  const uint32_t* Bs = (const uint32_t*)Bs4;

  const int tid  = threadIdx.x;
  const int lane = tid & 63;
  const int w    = tid >> 6;
  const int wm   = w >> 1, wn = w & 1;
  const int q    = lane >> 4;
  const int c    = lane & 15;

  /* per-lane A source addresses (pre-swizzled global, linear LDS dest) */
  const int* tokE = tok + e * CAP;
  const char* aptr[4];
#pragma unroll
  for (int it = 0; it < 4; ++it) {
    int p   = (w * 4 + it) * 64 + lane;
    int row = p >> 3, c8 = p & 7;
    int mrow = m0 + row; if (mrow >= cn) mrow = cn - 1;
    aptr[it] = (const char*)(xb + (size_t)tokE[mrow] * (HIDDEN / 8) + (c8 ^ (row & 7)));
  }
  const char* bptr = (const char*)wgub + ((size_t)(e * 56 + fb) * 16) * 16384u
                   + (size_t)w * 4096u + (size_t)lane * 16u;

  floatx4 acc[4][4];
#pragma unroll
  for (int i = 0; i < 4; ++i)
#pragma unroll
    for (int j = 0; j < 4; ++j) acc[i][j] = (floatx4){0.f, 0.f, 0.f, 0.f};

  for (int kt = 0; kt < HIDDEN / 64; ++kt) {
    __syncthreads();
#pragma unroll
    for (int it = 0; it < 4; ++it)
      ld_g2l16(aptr[it] + (size_t)kt * 128u, &As[(w * 4 + it) * 64]);
#pragma unroll
    for (int it = 0; it < 4; ++it)
      ld_g2l16(bptr + (size_t)kt * 16384u + (size_t)it * 1024u, &Bs4[(w * 4 + it) * 64]);
    __syncthreads();
#pragma unroll
    for (int ks = 0; ks < 2; ++ks) {
      short8 af[4];
#pragma unroll
      for (int i = 0; i < 4; ++i) {
        int row = wm * 64 + i * 16 + c;
        int kc8 = ks * 4 + q;
        af[i] = as_short8(As[row * 8 + (kc8 ^ (row & 7))]);
      }
      short8 bfr[4];
#pragma unroll
      for (int j = 0; j < 4; ++j) {
        int n  = wn * 64 + j * 16 + c;
        int kp = ks * 16 + q * 4;
        int nn = n ^ ((q & 1) << 4);
        bfr[j] = as_short8(make_uint4(Bs[(kp + 0) * 128 + nn], Bs[(kp + 1) * 128 + nn],
                                      Bs[(kp + 2) * 128 + nn], Bs[(kp + 3) * 128 + nn]));
      }
#pragma unroll
      for (int i = 0; i < 4; ++i)
#pragma unroll
        for (int j = 0; j < 4; ++j)
          acc[i][j] = __builtin_amdgcn_mfma_f32_16x16x32_bf16(af[i], bfr[j], acc[i][j], 0, 0, 0);
    }
  }

#pragma unroll
  for (int i = 0; i < 4; ++i) {
#pragma unroll
    for (int r = 0; r < 4; ++r) {
      int m = m0 + wm * 64 + i * 16 + q * 4 + r;
      if (m < cn) {
#pragma unroll
        for (int j = 0; j < 2; ++j) {
          float g = acc[i][j][r];
          float u = acc[i][j + 2][r];
          float a = (g / (1.f + __expf(-g))) * u;
          act[(size_t)(basev + m) * FFN + (f0 + wn * 32 + j * 16 + c)] = (unsigned short)f2bf(a);
        }
      }
    }
  }
}

/* ==== grouped GEMM 2 (fast) ==== */
__global__ __launch_bounds__(256) void moe_down(
    const unsigned short* __restrict__ act, const uint4* __restrict__ wdb,
    const int* __restrict__ cnt, const int* __restrict__ tok,
    const float* __restrict__ wgt, float* __restrict__ out)
{
  const int e  = blockIdx.z;
  const int m0 = blockIdx.y * 128;
  const int nb = blockIdx.x;
  const int n0 = nb * 128;
  const int cn = cnt[e];
  if (m0 >= cn) return;
  int basev = 0;
#pragma unroll
  for (int i = 0; i < NE; ++i) { int ci = cnt[i]; if (i < e) basev += ci; }

  __shared__ uint4 As[1024];
  __shared__ uint4 Bs4[1024];
  const uint32_t* Bs = (const uint32_t*)Bs4;

  const int tid  = threadIdx.x;
  const int lane = tid & 63;
  const int w    = tid >> 6;
  const int wm   = w >> 1, wn = w & 1;
  const int q    = lane >> 4;
  const int c    = lane & 15;

  const char* aptr[4];
#pragma unroll
  for (int it = 0; it < 4; ++it) {
    int p   = (w * 4 + it) * 64 + lane;
    int row = p >> 3, c8 = p & 7;
    int mrow = m0 + row; if (mrow >= cn) mrow = cn - 1;
    aptr[it] = (const char*)act +
               ((size_t)(basev + mrow) * FFN + (size_t)((c8 ^ (row & 7)) * 8)) * 2u;
  }
  const char* bptr = (const char*)wdb + ((size_t)(e * 8 + nb) * 56) * 16384u
                   + (size_t)w * 4096u + (size_t)lane * 16u;

  floatx4 acc[4][4];
#pragma unroll
  for (int i = 0; i < 4; ++i)
#pragma unroll
    for (int j = 0; j < 4; ++j) acc[i][j] = (floatx4){0.f, 0.f, 0.f, 0.f};

  for (int kt = 0; kt < FFN / 64; ++kt) {
    __syncthreads();
#pragma unroll
    for (int it = 0; it < 4; ++it)
      ld_g2l16(aptr[it] + (size_t)kt * 128u, &As[(w * 4 + it) * 64]);
#pragma unroll
    for (int it = 0; it < 4; ++it)
      ld_g2l16(bptr + (size_t)kt * 16384u + (size_t)it * 1024u, &Bs4[(w * 4 + it) * 64]);
    __syncthreads();
#pragma unroll
    for (int ks = 0; ks < 2; ++ks) {
      short8 af[4];
#pragma unroll
      for (int i = 0; i < 4; ++i) {
        int row = wm * 64 + i * 16 + c;
        int kc8 = ks * 4 + q;
        af[i] = as_short8(As[row * 8 + (kc8 ^ (row & 7))]);
      }
      short8 bfr[4];
#pragma unroll
      for (int j = 0; j < 4; ++j) {
        int n  = wn * 64 + j * 16 + c;
        int kp = ks * 16 + q * 4;
        int nn = n ^ ((q & 1) << 4);
        bfr[j] = as_short8(make_uint4(Bs[(kp + 0) * 128 + nn], Bs[(kp + 1) * 128 + nn],
                                      Bs[(kp + 2) * 128 + nn], Bs[(kp + 3) * 128 + nn]));
      }
#pragma unroll
      for (int i = 0; i < 4; ++i)
#pragma unroll
        for (int j = 0; j < 4; ++j)
          acc[i][j] = __builtin_amdgcn_mfma_f32_16x16x32_bf16(af[i], bfr[j], acc[i][j], 0, 0, 0);
    }
  }

#pragma unroll
  for (int i = 0; i < 4; ++i) {
#pragma unroll
    for (int r = 0; r < 4; ++r) {
      int m = m0 + wm * 64 + i * 16 + q * 4 + r;
      if (m < cn) {
        int   t  = tok[e * CAP + m];
        float wg = wgt[e * CAP + m];
        float* orow = out + (size_t)t * HIDDEN + n0 + wn * 64 + c;
#pragma unroll
        for (int j = 0; j < 4; ++j)
          atomicAdd(orow + j * 16, acc[i][j][r] * wg);
      }
    }
  }
}

/* ==== legacy fallback GEMMs (baseline, in-loop fp32->bf16) — used only if
 *      the workspace cannot hold the preconverted bf16 weights.           ==== */
__global__ __launch_bounds__(256) void moe_gateup_lg(
    const uint4* __restrict__ xb, const float* __restrict__ wgu,
    const int* __restrict__ cnt, const int* __restrict__ tok,
    unsigned short* __restrict__ act)
{
  const int e  = blockIdx.z;
  const int m0 = blockIdx.y * 128;
  const int f0 = blockIdx.x * 64;
  const int cn = cnt[e];
  if (m0 >= cn) return;
  int basev = 0;
#pragma unroll
  for (int i = 0; i < NE; ++i) { int ci = cnt[i]; if (i < e) basev += ci; }

  __shared__ uint4    As[1024];
  __shared__ uint32_t Bs[4096];

  const int tid  = threadIdx.x;
  const int lane = tid & 63;
  const int w    = tid >> 6;
  const int wm   = w >> 1, wn = w & 1;
  const int q    = lane >> 4;
  const int c    = lane & 15;

  floatx4 acc[4][4];
#pragma unroll
  for (int i = 0; i < 4; ++i)
#pragma unroll
    for (int j = 0; j < 4; ++j) acc[i][j] = (floatx4){0.f, 0.f, 0.f, 0.f};

  const float* wB  = wgu + (size_t)e * HIDDEN * (2 * FFN);
  const int* tokE  = tok + e * CAP;

  for (int kt = 0; kt < HIDDEN / 64; ++kt) {
    const int k0 = kt * 64;
    __syncthreads();
#pragma unroll
    for (int it = 0; it < 4; ++it) {
      int cid = it * 256 + tid;
      int row = cid >> 3, c8 = cid & 7;
      int mrow = m0 + row; if (mrow >= cn) mrow = cn - 1;
      int tk = tokE[mrow];
      As[row * 8 + (c8 ^ (row & 7))] = xb[(size_t)tk * (HIDDEN / 8) + (k0 >> 3) + c8];
    }
#pragma unroll
    for (int it = 0; it < 4; ++it) {
      int mid = it * 256 + tid;
      int kp = mid >> 5;
      int n  = (mid & 31) * 4;
      int col = f0 + ((n >> 6) << 5) + (n & 31) + (((n >> 5) & 1) ? FFN : 0);
      const float* src = wB + (size_t)(k0 + 2 * kp) * (2 * FFN) + col;
      float4 r0 = *(const float4*)src;
      float4 r1 = *(const float4*)(src + 2 * FFN);
      int widx = kp * 128 + (n ^ (((kp >> 2) & 1) << 4));
      *(uint4*)&Bs[widx] = make_uint4(pack2(r0.x, r1.x), pack2(r0.y, r1.y),
                                      pack2(r0.z, r1.z), pack2(r0.w, r1.w));
    }
    __syncthreads();
#pragma unroll
    for (int ks = 0; ks < 2; ++ks) {
      short8 af[4];
#pragma unroll
      for (int i = 0; i < 4; ++i) {
        int row = wm * 64 + i * 16 + c;
        int kc8 = ks * 4 + q;
        af[i] = as_short8(As[row * 8 + (kc8 ^ (row & 7))]);
      }
      short8 bfr[4];
#pragma unroll
      for (int j = 0; j < 4; ++j) {
        int n  = wn * 64 + j * 16 + c;
        int kp = ks * 16 + q * 4;
        int nn = n ^ ((q & 1) << 4);
        bfr[j] = as_short8(make_uint4(Bs[(kp + 0) * 128 + nn], Bs[(kp + 1) * 128 + nn],
                                      Bs[(kp + 2) * 128 + nn], Bs[(kp + 3) * 128 + nn]));
      }
#pragma unroll
      for (int i = 0; i < 4; ++i)
#pragma unroll
        for (int j = 0; j < 4; ++j)
          acc[i][j] = __builtin_amdgcn_mfma_f32_16x16x32_bf16(af[i], bfr[j], acc[i][j], 0, 0, 0);
    }
  }

#pragma unroll
  for (int i = 0; i < 4; ++i) {
#pragma unroll
    for (int r = 0; r < 4; ++r) {
      int m = m0 + wm * 64 + i * 16 + q * 4 + r;
      if (m < cn) {
#pragma unroll
        for (int j = 0; j < 2; ++j) {
          float g = acc[i][j][r];
          float u = acc[i][j + 2][r];
          float a = (g / (1.f + __expf(-g))) * u;
          act[(size_t)(basev + m) * FFN + (f0 + wn * 32 + j * 16 + c)] = (unsigned short)f2bf(a);
        }
      }
    }
  }
}

__global__ __launch_bounds__(256) void moe_down_lg(
    const uint4* __restrict__ actc, const float* __restrict__ wd,
    const int* __restrict__ cnt, const int* __restrict__ tok,
    const float* __restrict__ wgt, float* __restrict__ out)
{
  const int e  = blockIdx.z;
  const int m0 = blockIdx.y * 128;
  const int n0 = blockIdx.x * 128;
  const int cn = cnt[e];
  if (m0 >= cn) return;
  int basev = 0;
#pragma unroll
  for (int i = 0; i < NE; ++i) { int ci = cnt[i]; if (i < e) basev += ci; }

  __shared__ uint4    As[1024];
  __shared__ uint32_t Bs[4096];

  const int tid  = threadIdx.x;
  const int lane = tid & 63;
  const int w    = tid >> 6;
  const int wm   = w >> 1, wn = w & 1;
  const int q    = lane >> 4;
  const int c    = lane & 15;

  floatx4 acc[4][4];
#pragma unroll
  for (int i = 0; i < 4; ++i)
#pragma unroll
    for (int j = 0; j < 4; ++j) acc[i][j] = (floatx4){0.f, 0.f, 0.f, 0.f};

  const float* wB = wd + (size_t)e * FFN * HIDDEN;

  for (int kt = 0; kt < FFN / 64; ++kt) {
    const int k0 = kt * 64;
    __syncthreads();
#pragma unroll
    for (int it = 0; it < 4; ++it) {
      int cid = it * 256 + tid;
      int row = cid >> 3, c8 = cid & 7;
      int mrow = m0 + row; if (mrow >= cn) mrow = cn - 1;
      As[row * 8 + (c8 ^ (row & 7))] =
          actc[(size_t)(basev + mrow) * (FFN / 8) + (k0 >> 3) + c8];
    }
#pragma unroll
    for (int it = 0; it < 4; ++it) {
      int mid = it * 256 + tid;
      int kp = mid >> 5;
      int n  = (mid & 31) * 4;
      int col = n0 + n;
      const float* src = wB + (size_t)(k0 + 2 * kp) * HIDDEN + col;
      float4 r0 = *(const float4*)src;
      float4 r1 = *(const float4*)(src + HIDDEN);
      int widx = kp * 128 + (n ^ (((kp >> 2) & 1) << 4));
      *(uint4*)&Bs[widx] = make_uint4(pack2(r0.x, r1.x), pack2(r0.y, r1.y),
                                      pack2(r0.z, r1.z), pack2(r0.w, r1.w));
    }
    __syncthreads();
#pragma unroll
    for (int ks = 0; ks < 2; ++ks) {
      short8 af[4];
#pragma unroll
      for (int i = 0; i < 4; ++i) {
        int row = wm * 64 + i * 16 + c;
        int kc8 = ks * 4 + q;
        af[i] = as_short8(As[row * 8 + (kc8 ^ (row & 7))]);
      }
      short8 bfr[4];
#pragma unroll
      for (int j = 0; j < 4; ++j) {
        int n  = wn * 64 + j * 16 + c;
        int kp = ks * 16 + q * 4;
        int nn = n ^ ((q & 1) << 4);
        bfr[j] = as_short8(make_uint4(Bs[(kp + 0) * 128 + nn], Bs[(kp + 1) * 128 + nn],
                                      Bs[(kp + 2) * 128 + nn], Bs[(kp + 3) * 128 + nn]));
      }
#pragma unroll
      for (int i = 0; i < 4; ++i)
#pragma unroll
        for (int j = 0; j < 4; ++j)
          acc[i][j] = __builtin_amdgcn_mfma_f32_16x16x32_bf16(af[i], bfr[j], acc[i][j], 0, 0, 0);
    }
  }

#pragma unroll
  for (int i = 0; i < 4; ++i) {
#pragma unroll
    for (int r = 0; r < 4; ++r) {
      int m = m0 + wm * 64 + i * 16 + q * 4 + r;
      if (m < cn) {
        int   t  = tok[e * CAP + m];
        float wg = wgt[e * CAP + m];
        float* orow = out + (size_t)t * HIDDEN + n0 + wn * 64 + c;
#pragma unroll
        for (int j = 0; j < 4; ++j)
          atomicAdd(orow + j * 16, acc[i][j][r] * wg);
      }
    }
  }
}

extern "C" void kernel_launch(void* const* d_in, const int* in_sizes, int n_in,
                              void* d_out, int out_size, void* d_ws, size_t ws_size,
                              hipStream_t stream)
{
  (void)in_sizes; (void)n_in; (void)out_size;
  const float* x   = (const float*)d_in[0];
  const float* gw  = (const float*)d_in[1];
  const float* wgu = (const float*)d_in[2];
  const float* wd  = (const float*)d_in[3];
  float* out = (float*)d_out;
  char*  ws  = (char*)d_ws;

  uint4*          xb   = (uint4*)(ws + X_OFF);
  int*            cnt  = (int*)(ws + CNT_OFF);
  int*            tok  = (int*)(ws + TOK_OFF);
  float*          wgt  = (float*)(ws + WGT_OFF);
  unsigned short* act  = (unsigned short*)(ws + ACT_OFF);
  uint4*          wgub = (uint4*)(ws + WGU_OFF);
  uint4*          wdb  = (uint4*)(ws + WDB_OFF);

  const bool fast = (ws_size >= WS_NEED);

  moe_prep<<<OUT_ELEMS / (256 * 4), 256, 0, stream>>>((float4*)out, cnt);
  moe_convert<<<(NTOK * HIDDEN) / (256 * 8), 256, 0, stream>>>((const float4*)x, xb);
  moe_router<<<NTOK / 4, 256, 0, stream>>>(x, gw, out + OUT_ELEMS, cnt, tok, wgt);

  if (fast) {
    moe_wconv_gu<<<dim3(16, 56, NE), 256, 0, stream>>>(wgu, wgub);
    moe_wconv_d<<<dim3(56, 8, NE), 256, 0, stream>>>(wd, wdb);
    moe_gateup<<<dim3(FFN / 64, 16, NE), 256, 0, stream>>>(xb, wgub, cnt, tok, act);
    moe_down<<<dim3(HIDDEN / 128, 16, NE), 256, 0, stream>>>(act, wdb, cnt, tok, wgt, out);
  } else {
    moe_gateup_lg<<<dim3(FFN / 64, 16, NE), 256, 0, stream>>>(xb, wgu, cnt, tok, act);
    moe_down_lg<<<dim3(HIDDEN / 128, 16, NE), 256, 0, stream>>>((const uint4*)act, wd, cnt, tok, wgt, out);
  }
}